// Round 1
// baseline (448.325 us; speedup 1.0000x reference)
//
#include <hip/hip_runtime.h>
#include <math.h>

// ---------------- constants (shapes fixed by the reference) ----------------
#define IN_CH   256
#define HC      256   // H*C
#define H_HEADS 4
#define NEG_SLOPE 0.2f
#define SCAN_T  1024

typedef __attribute__((ext_vector_type(8))) short short8;
typedef __attribute__((ext_vector_type(4))) short short4v;
typedef __attribute__((ext_vector_type(4))) float float4v;

// ---------------- helpers ----------------
__device__ __forceinline__ float bf2f(unsigned short b) {
    return __uint_as_float(((unsigned)b) << 16);
}
__device__ __forceinline__ unsigned short f2bf(float f) {
    unsigned u = __float_as_uint(f);
    u += 0x7fffu + ((u >> 16) & 1u);    // round-to-nearest-even
    return (unsigned short)(u >> 16);
}
__device__ __forceinline__ float lrelu(float a) {
    return a >= 0.f ? a : NEG_SLOPE * a;
}

// ---------------- kernels ----------------

// W (fp32, [256k x 256c] row-major) -> transposed bf16 (wt[c][k])
__global__ void prep_w(const float* __restrict__ w,
                       unsigned short* __restrict__ wt) {
    int idx = blockIdx.x * 256 + threadIdx.x;   // 65536 total
    int k = idx >> 8, c = idx & 255;
    wt[(size_t)c * 256 + k] = f2bf(w[idx]);
}

// x (fp32) -> bf16 hi/lo split, streaming.
__global__ __launch_bounds__(256) void prep_x(const float* __restrict__ x,
                                              unsigned short* __restrict__ x_hi,
                                              unsigned short* __restrict__ x_lo,
                                              int total4) {
    int i = blockIdx.x * 256 + threadIdx.x;
    if (i >= total4) return;
    float4v v = ((const float4v*)x)[i];
    short4v hi, lo;
#pragma unroll
    for (int j = 0; j < 4; ++j) {
        unsigned short h = f2bf(v[j]);
        hi[j] = (short)h;
        lo[j] = (short)f2bf(v[j] - bf2f(h));
    }
    ((short4v*)x_hi)[i] = hi;
    ((short4v*)x_lo)[i] = lo;
}

// xh = x @ W. Block = 16 rows x 256 cols (4 waves = 4 heads): x fetched ONCE.
// A-tile (16 rows x 256 k, hi+lo bf16 = 16 KB) staged to LDS via plain
// global-load -> ds_write_b128 (graph-capture-safe; round-7's
// global_load_lds variant diverged under graph replay). Chunk-transposed
// layout [kc][m]: slot q holds row (q&15), k-chunk (q>>4)&31; ds_read_b128
// A-fragments are 2-way bank-aliased (free). 2 MFMAs per fragment
// (a_hi*bh + a_lo*bh; a_hi*b_lo term ~6e-4, dropped).
// Epilogue fuses node_attn (complete per-head dots via 16-lane shfl).
__global__ __launch_bounds__(256) void gemm_xh(const unsigned short* __restrict__ x_hi,
                                               const unsigned short* __restrict__ x_lo,
                                               const unsigned short* __restrict__ wt,
                                               const float* __restrict__ att_s,
                                               const float* __restrict__ att_d,
                                               unsigned short* __restrict__ xh_bf,
                                               float* __restrict__ a_src,
                                               float* __restrict__ a_dst, int N) {
    __shared__ __attribute__((aligned(16))) unsigned char lds_a[16384];
    int tid  = threadIdx.x;
    int wave = tid >> 6;            // == head index
    int lane = tid & 63;
    int quad = lane >> 4;
    int l16  = lane & 15;
    int rb   = blockIdx.x * 16;

    // ---- stage A-tile: 1024 slots x 16 B; slots [0,512) hi, [512,1024) lo ----
#pragma unroll
    for (int pass = 0; pass < 4; ++pass) {
        int q    = pass * 256 + tid;
        int half = q >> 9;                      // 0 = hi, 1 = lo
        int s    = q & 511;
        int kc   = s >> 4;                      // 16-B chunk index (k/8)
        int m    = s & 15;                      // row within tile
        int grow = rb + m; if (grow >= N) grow = N - 1;
        const unsigned short* gp =
            (half ? x_lo : x_hi) + (size_t)grow * IN_CH + kc * 8;
        short8 v = *(const short8*)gp;
        *(short8*)(lds_a + (size_t)q * 16) = v;
    }
    __syncthreads();

    // ---- K-loop: 8 x { 2 ds_read_b128 + 4 x (1 B-load + 2 MFMA) } ----
    float4v acc[4] = {};
    const unsigned short* wt_base = wt + ((size_t)wave * 64 + l16) * IN_CH;
#pragma unroll
    for (int k0 = 0; k0 < 8; ++k0) {
        int kc   = k0 * 4 + quad;
        int slot = kc * 16 + l16;
        short8 a_hi = *(const short8*)(lds_a + slot * 16);
        short8 a_lo = *(const short8*)(lds_a + 8192 + slot * 16);
#pragma unroll
        for (int ct = 0; ct < 4; ++ct) {
            short8 bh = *(const short8*)(wt_base + (size_t)ct * 16 * IN_CH
                                         + k0 * 32 + quad * 8);
            acc[ct] = __builtin_amdgcn_mfma_f32_16x16x32_bf16(a_lo, bh, acc[ct], 0, 0, 0);
            acc[ct] = __builtin_amdgcn_mfma_f32_16x16x32_bf16(a_hi, bh, acc[ct], 0, 0, 0);
        }
    }

    // ---- epilogue: xh store + fused a_src/a_dst (head = wave) ----
    int cb = wave;
    float ps[4] = {0.f, 0.f, 0.f, 0.f};
    float pd[4] = {0.f, 0.f, 0.f, 0.f};
#pragma unroll
    for (int ct = 0; ct < 4; ++ct) {
        float as_c = att_s[cb * 64 + ct * 16 + l16];
        float ad_c = att_d[cb * 64 + ct * 16 + l16];
#pragma unroll
        for (int r = 0; r < 4; ++r) {
            float v = acc[ct][r];
            int grow = rb + quad * 4 + r;
            if (grow < N)
                xh_bf[(size_t)grow * HC + cb * 64 + ct * 16 + l16] = f2bf(v);
            ps[r] += v * as_c;
            pd[r] += v * ad_c;
        }
    }
#pragma unroll
    for (int off = 1; off < 16; off <<= 1) {
#pragma unroll
        for (int r = 0; r < 4; ++r) {
            ps[r] += __shfl_xor(ps[r], off);
            pd[r] += __shfl_xor(pd[r], off);
        }
    }
    if (l16 == 0) {
#pragma unroll
        for (int r = 0; r < 4; ++r) {
            int grow = rb + quad * 4 + r;
            if (grow < N) {
                a_src[(size_t)grow * 4 + cb] = ps[r];
                a_dst[(size_t)grow * 4 + cb] = pd[r];
            }
        }
    }
}

// degree histogram over dst
__global__ __launch_bounds__(256) void deg_count(const int* __restrict__ ei,
                                                 int* __restrict__ deg, int E) {
    int e = blockIdx.x * 256 + threadIdx.x;
    if (e >= E) return;
    atomicAdd(deg + ei[E + e], 1);
}

// single-block exclusive scan of deg[N] -> rowptr, cursor
__global__ __launch_bounds__(SCAN_T) void scan_rowptr(const int* __restrict__ deg,
                                                      int* __restrict__ rowptr,
                                                      int* __restrict__ cursor, int N) {
    __shared__ int part[SCAN_T];
    int t = threadIdx.x;
    int chunk = (N + SCAN_T - 1) / SCAN_T;
    int lo = t * chunk, hi = min(lo + chunk, N);
    int s = 0;
    for (int i = lo; i < hi; ++i) s += deg[i];
    part[t] = s;
    __syncthreads();
    for (int off = 1; off < SCAN_T; off <<= 1) {
        int tmp = (t >= off) ? part[t - off] : 0;
        __syncthreads();
        part[t] += tmp;
        __syncthreads();
    }
    int running = part[t] - s;   // exclusive prefix of this chunk
    for (int i = lo; i < hi; ++i) {
        rowptr[i] = running;
        cursor[i] = running;
        running += deg[i];
    }
}

// fill CSR: csr_src[slot] = src id, slots allocated per-dst via cursor atomics
__global__ __launch_bounds__(256) void fill_csr(const int* __restrict__ ei,
                                                int* __restrict__ cursor,
                                                int* __restrict__ csr_src, int E) {
    int e = blockIdx.x * 256 + threadIdx.x;
    if (e >= E) return;
    int s = ei[e], d = ei[E + e];
    int slot = atomicAdd(cursor + d, 1);
    csr_src[slot] = s;
}

// one wave per dst: online-softmax gather, UNROLL-2 (independent even/odd
// states merged at the end -> 2 xh rows in flight). Emits out row + packed
// per-dst {a_dst, m, 1/(l+eps)} (12 floats) for att_edge.
__global__ __launch_bounds__(256) void gat_gather(const int* __restrict__ csr_src,
                                                  const int* __restrict__ rowptr,
                                                  const int* __restrict__ deg,
                                                  const float* __restrict__ a_src,
                                                  const float* __restrict__ a_dst,
                                                  const unsigned short* __restrict__ xh_bf,
                                                  float* __restrict__ out,
                                                  float* __restrict__ pack, int N) {
    int wave = threadIdx.x >> 6, lane = threadIdx.x & 63;
    int d = blockIdx.x * 4 + wave;
    if (d >= N) return;
    int h = lane >> 4;
    int start = rowptr[d], cnt = deg[d];
    float adst = a_dst[(size_t)d * 4 + h];

    if (cnt == 0) {
        *(float4v*)(out + (size_t)d * HC + lane * 4) = (float4v){0.f, 0.f, 0.f, 0.f};
        if ((lane & 15) == 0) {   // write pack anyway: no poison ever readable
            pack[(size_t)d * 12 + h]     = adst;
            pack[(size_t)d * 12 + 4 + h] = 0.f;
            pack[(size_t)d * 12 + 8 + h] = 0.f;
        }
        return;
    }

    float mE = -INFINITY, lE = 0.f, mO = -INFINITY, lO = 0.f;
    float4v accE = {0.f, 0.f, 0.f, 0.f}, accO = {0.f, 0.f, 0.f, 0.f};

    int s2 = 0, s3 = 0;
    float asE = 0.f, asO = 0.f;
    short4v xvE = {}, xvO = {};
    {
        int s0 = csr_src[start];
        asE = a_src[(size_t)s0 * 4 + h];
        xvE = *(const short4v*)(xh_bf + (size_t)s0 * HC + lane * 4);
    }
    if (cnt > 1) {
        int s1 = csr_src[start + 1];
        asO = a_src[(size_t)s1 * 4 + h];
        xvO = *(const short4v*)(xh_bf + (size_t)s1 * HC + lane * 4);
    }
    if (cnt > 2) s2 = csr_src[start + 2];
    if (cnt > 3) s3 = csr_src[start + 3];

    for (int i = 0; i < cnt; i += 2) {
        // prefetch data for edges i+2,i+3; ids for i+4,i+5
        float asE_n = 0.f, asO_n = 0.f;
        short4v xvE_n = {}, xvO_n = {};
        if (i + 2 < cnt) {
            asE_n = a_src[(size_t)s2 * 4 + h];
            xvE_n = *(const short4v*)(xh_bf + (size_t)s2 * HC + lane * 4);
        }
        if (i + 3 < cnt) {
            asO_n = a_src[(size_t)s3 * 4 + h];
            xvO_n = *(const short4v*)(xh_bf + (size_t)s3 * HC + lane * 4);
        }
        int s4 = (i + 4 < cnt) ? csr_src[start + i + 4] : 0;
        int s5 = (i + 5 < cnt) ? csr_src[start + i + 5] : 0;
        // compute edge i (E state)
        {
            float al = lrelu(asE + adst);
            float mn = fmaxf(mE, al);
            float sc = __expf(mE - mn);
            float p  = __expf(al - mn);
            lE = lE * sc + p;
#pragma unroll
            for (int j = 0; j < 4; ++j)
                accE[j] = accE[j] * sc + p * bf2f((unsigned short)xvE[j]);
            mE = mn;
        }
        // compute edge i+1 (O state)
        if (i + 1 < cnt) {
            float al = lrelu(asO + adst);
            float mn = fmaxf(mO, al);
            float sc = __expf(mO - mn);
            float p  = __expf(al - mn);
            lO = lO * sc + p;
#pragma unroll
            for (int j = 0; j < 4; ++j)
                accO[j] = accO[j] * sc + p * bf2f((unsigned short)xvO[j]);
            mO = mn;
        }
        asE = asE_n; xvE = xvE_n; asO = asO_n; xvO = xvO_n;
        s2 = s4; s3 = s5;
    }
    // merge states (mE finite since cnt >= 1; empty O contributes 0)
    float mm = fmaxf(mE, mO);
    float sE = __expf(mE - mm), sO = __expf(mO - mm);
    float l  = lE * sE + lO * sO;
    float inv = 1.f / (l + 1e-16f);
    float4v o;
#pragma unroll
    for (int j = 0; j < 4; ++j) o[j] = (accE[j] * sE + accO[j] * sO) * inv;
    *(float4v*)(out + (size_t)d * HC + lane * 4) = o;
    if ((lane & 15) == 0) {
        pack[(size_t)d * 12 + h]     = adst;
        pack[(size_t)d * 12 + 4 + h] = mm;
        pack[(size_t)d * 12 + 8 + h] = inv;
    }
}

// att[e,:] = exp(lrelu(a_src[s]+a_dst[d]) - m[d]) * inv_l[d]; packed dst reads
__global__ __launch_bounds__(256) void att_edge(const int* __restrict__ ei,
                                                const float* __restrict__ a_src,
                                                const float* __restrict__ pack,
                                                float* __restrict__ att_out, int E) {
    int e = blockIdx.x * 256 + threadIdx.x;
    if (e >= E) return;
    int s = ei[e], d = ei[E + e];
    float4v as = *(const float4v*)(a_src + (size_t)s * 4);
    float4v ad = *(const float4v*)(pack + (size_t)d * 12);
    float4v mm = *(const float4v*)(pack + (size_t)d * 12 + 4);
    float4v gg = *(const float4v*)(pack + (size_t)d * 12 + 8);
    float4v o;
#pragma unroll
    for (int h = 0; h < 4; ++h)
        o[h] = __expf(lrelu(as[h] + ad[h]) - mm[h]) * gg[h];
    *(float4v*)(att_out + (size_t)e * 4) = o;
}

// ---------------- launcher ----------------
extern "C" void kernel_launch(void* const* d_in, const int* in_sizes, int n_in,
                              void* d_out, int out_size, void* d_ws, size_t ws_size,
                              hipStream_t stream) {
    const float* x     = (const float*)d_in[0];  // fp32 [N,256]
    const int*   ei    = (const int*)d_in[1];    // int32 [2,E]
    const float* W     = (const float*)d_in[2];  // fp32 [256,256]
    const float* att_s = (const float*)d_in[3];  // fp32 [4,64]
    const float* att_d = (const float*)d_in[4];  // fp32 [4,64]

    const int N = in_sizes[0] / IN_CH;   // 50000
    const int E = in_sizes[1] / 2;       // 800000

    char* ws = (char*)d_ws;
    size_t off = 0;
    unsigned short* xh_bf = (unsigned short*)(ws + off); off += (size_t)N * HC * 2;
    unsigned short* x_hi  = (unsigned short*)(ws + off); off += (size_t)N * IN_CH * 2;
    unsigned short* x_lo  = (unsigned short*)(ws + off); off += (size_t)N * IN_CH * 2;
    unsigned short* wt    = (unsigned short*)(ws + off); off += (size_t)IN_CH * HC * 2;
    float* a_src = (float*)(ws + off); off += (size_t)N * H_HEADS * 4;
    float* a_dst = (float*)(ws + off); off += (size_t)N * H_HEADS * 4;
    float* pack  = (float*)(ws + off); off += (size_t)N * 12 * 4;
    int* rowptr  = (int*)(ws + off); off += (size_t)N * 4;
    int* cursor  = (int*)(ws + off); off += (size_t)N * 4;
    int* csr_src = (int*)(ws + off); off += (size_t)E * 4;
    size_t zoff = off;  // zero-init region
    int* deg     = (int*)(ws + off); off += (size_t)N * 4;

    float* out     = (float*)d_out;            // [N, 256] fp32
    float* out_att = out + (size_t)N * HC;     // [E, 4]   fp32

    hipMemsetAsync(ws + zoff, 0, off - zoff, stream);  // deg only

    prep_w<<<256, 256, 0, stream>>>(W, wt);
    prep_x<<<(N * IN_CH / 4 + 255) / 256, 256, 0, stream>>>(x, x_hi, x_lo, N * IN_CH / 4);
    deg_count<<<(E + 255) / 256, 256, 0, stream>>>(ei, deg, E);
    gemm_xh<<<(N + 15) / 16, 256, 0, stream>>>(x_hi, x_lo, wt, att_s, att_d,
                                               xh_bf, a_src, a_dst, N);
    scan_rowptr<<<1, SCAN_T, 0, stream>>>(deg, rowptr, cursor, N);
    fill_csr<<<(E + 255) / 256, 256, 0, stream>>>(ei, cursor, csr_src, E);
    gat_gather<<<(N + 3) / 4, 256, 0, stream>>>(csr_src, rowptr, deg, a_src, a_dst,
                                                xh_bf, out, pack, N);
    att_edge<<<(E + 255) / 256, 256, 0, stream>>>(ei, a_src, pack, out_att, E);
}

// Round 2
// 347.826 us; speedup vs baseline: 1.2889x; 1.2889x over previous
//
#include <hip/hip_runtime.h>
#include <math.h>

// ---------------- constants (shapes fixed by the reference) ----------------
#define IN_CH   256
#define HC      256   // H*C
#define H_HEADS 4
#define NEG_SLOPE 0.2f

typedef __attribute__((ext_vector_type(8))) short short8;
typedef __attribute__((ext_vector_type(4))) short short4v;
typedef __attribute__((ext_vector_type(4))) float float4v;

// ---------------- helpers ----------------
__device__ __forceinline__ float bf2f(unsigned short b) {
    return __uint_as_float(((unsigned)b) << 16);
}
__device__ __forceinline__ unsigned short f2bf(float f) {
    unsigned u = __float_as_uint(f);
    u += 0x7fffu + ((u >> 16) & 1u);    // round-to-nearest-even
    return (unsigned short)(u >> 16);
}
__device__ __forceinline__ float lrelu(float a) {
    return a >= 0.f ? a : NEG_SLOPE * a;
}

// ---------------- kernels ----------------

// W (fp32, [256k x 256c] row-major) -> transposed bf16 (wt[c][k])
__global__ void prep_w(const float* __restrict__ w,
                       unsigned short* __restrict__ wt) {
    int idx = blockIdx.x * 256 + threadIdx.x;   // 65536 total
    int k = idx >> 8, c = idx & 255;
    wt[(size_t)c * 256 + k] = f2bf(w[idx]);
}

// x (fp32) -> bf16 hi/lo split, streaming.
__global__ __launch_bounds__(256) void prep_x(const float* __restrict__ x,
                                              unsigned short* __restrict__ x_hi,
                                              unsigned short* __restrict__ x_lo,
                                              int total4) {
    int i = blockIdx.x * 256 + threadIdx.x;
    if (i >= total4) return;
    float4v v = ((const float4v*)x)[i];
    short4v hi, lo;
#pragma unroll
    for (int j = 0; j < 4; ++j) {
        unsigned short h = f2bf(v[j]);
        hi[j] = (short)h;
        lo[j] = (short)f2bf(v[j] - bf2f(h));
    }
    ((short4v*)x_hi)[i] = hi;
    ((short4v*)x_lo)[i] = lo;
}

// xh = x @ W. Block = 16 rows x 256 cols (4 waves = 4 heads): x fetched ONCE.
// A-tile (16 rows x 256 k, hi+lo bf16 = 16 KB) staged to LDS via plain
// global-load -> ds_write_b128 (graph-capture-safe). Chunk-transposed
// layout [kc][m]. 2 MFMAs per fragment (a_hi*bh + a_lo*bh).
// Epilogue fuses node_attn (complete per-head dots via 16-lane shfl).
__global__ __launch_bounds__(256) void gemm_xh(const unsigned short* __restrict__ x_hi,
                                               const unsigned short* __restrict__ x_lo,
                                               const unsigned short* __restrict__ wt,
                                               const float* __restrict__ att_s,
                                               const float* __restrict__ att_d,
                                               unsigned short* __restrict__ xh_bf,
                                               float* __restrict__ a_src,
                                               float* __restrict__ a_dst, int N) {
    __shared__ __attribute__((aligned(16))) unsigned char lds_a[16384];
    int tid  = threadIdx.x;
    int wave = tid >> 6;            // == head index
    int lane = tid & 63;
    int quad = lane >> 4;
    int l16  = lane & 15;
    int rb   = blockIdx.x * 16;

    // ---- stage A-tile: 1024 slots x 16 B; slots [0,512) hi, [512,1024) lo ----
#pragma unroll
    for (int pass = 0; pass < 4; ++pass) {
        int q    = pass * 256 + tid;
        int half = q >> 9;                      // 0 = hi, 1 = lo
        int s    = q & 511;
        int kc   = s >> 4;                      // 16-B chunk index (k/8)
        int m    = s & 15;                      // row within tile
        int grow = rb + m; if (grow >= N) grow = N - 1;
        const unsigned short* gp =
            (half ? x_lo : x_hi) + (size_t)grow * IN_CH + kc * 8;
        short8 v = *(const short8*)gp;
        *(short8*)(lds_a + (size_t)q * 16) = v;
    }
    __syncthreads();

    // ---- K-loop: 8 x { 2 ds_read_b128 + 4 x (1 B-load + 2 MFMA) } ----
    float4v acc[4] = {};
    const unsigned short* wt_base = wt + ((size_t)wave * 64 + l16) * IN_CH;
#pragma unroll
    for (int k0 = 0; k0 < 8; ++k0) {
        int kc   = k0 * 4 + quad;
        int slot = kc * 16 + l16;
        short8 a_hi = *(const short8*)(lds_a + slot * 16);
        short8 a_lo = *(const short8*)(lds_a + 8192 + slot * 16);
#pragma unroll
        for (int ct = 0; ct < 4; ++ct) {
            short8 bh = *(const short8*)(wt_base + (size_t)ct * 16 * IN_CH
                                         + k0 * 32 + quad * 8);
            acc[ct] = __builtin_amdgcn_mfma_f32_16x16x32_bf16(a_lo, bh, acc[ct], 0, 0, 0);
            acc[ct] = __builtin_amdgcn_mfma_f32_16x16x32_bf16(a_hi, bh, acc[ct], 0, 0, 0);
        }
    }

    // ---- epilogue: xh store + fused a_src/a_dst (head = wave) ----
    int cb = wave;
    float ps[4] = {0.f, 0.f, 0.f, 0.f};
    float pd[4] = {0.f, 0.f, 0.f, 0.f};
#pragma unroll
    for (int ct = 0; ct < 4; ++ct) {
        float as_c = att_s[cb * 64 + ct * 16 + l16];
        float ad_c = att_d[cb * 64 + ct * 16 + l16];
#pragma unroll
        for (int r = 0; r < 4; ++r) {
            float v = acc[ct][r];
            int grow = rb + quad * 4 + r;
            if (grow < N)
                xh_bf[(size_t)grow * HC + cb * 64 + ct * 16 + l16] = f2bf(v);
            ps[r] += v * as_c;
            pd[r] += v * ad_c;
        }
    }
#pragma unroll
    for (int off = 1; off < 16; off <<= 1) {
#pragma unroll
        for (int r = 0; r < 4; ++r) {
            ps[r] += __shfl_xor(ps[r], off);
            pd[r] += __shfl_xor(pd[r], off);
        }
    }
    if (l16 == 0) {
#pragma unroll
        for (int r = 0; r < 4; ++r) {
            int grow = rb + quad * 4 + r;
            if (grow < N) {
                a_src[(size_t)grow * 4 + cb] = ps[r];
                a_dst[(size_t)grow * 4 + cb] = pd[r];
            }
        }
    }
}

// degree histogram over dst
__global__ __launch_bounds__(256) void deg_count(const int* __restrict__ ei,
                                                 int* __restrict__ deg, int E) {
    int e = blockIdx.x * 256 + threadIdx.x;
    if (e >= E) return;
    atomicAdd(deg + ei[E + e], 1);
}

// ---- device-wide exclusive scan of deg[N] -> rowptr, cursor (3 phases) ----
// Replaces the single-block scan_rowptr (was 110 us = 25% of total:
// OccupancyPercent 0.14, one CU). Each phase has full-grid parallelism.

// phase 1: per-block sums (1024 elements / block)
__global__ __launch_bounds__(256) void scan_part(const int* __restrict__ deg,
                                                 int* __restrict__ part, int N) {
    int t = threadIdx.x;
    int base = blockIdx.x * 1024 + t * 4;
    int s = 0;
    if (base + 4 <= N) {
        int4 v = *(const int4*)(deg + base);
        s = v.x + v.y + v.z + v.w;
    } else {
#pragma unroll
        for (int j = 0; j < 4; ++j)
            if (base + j < N) s += deg[base + j];
    }
#pragma unroll
    for (int off = 1; off < 64; off <<= 1) s += __shfl_xor(s, off);
    __shared__ int ws[4];
    if ((t & 63) == 0) ws[t >> 6] = s;
    __syncthreads();
    if (t == 0) part[blockIdx.x] = ws[0] + ws[1] + ws[2] + ws[3];
}

// phase 2: exclusive scan of part[NB] (NB <= 1024) in one block
__global__ __launch_bounds__(1024) void scan_mid(int* __restrict__ part, int NB) {
    __shared__ int sm[1024];
    int t = threadIdx.x;
    int v = (t < NB) ? part[t] : 0;
    sm[t] = v;
    __syncthreads();
    for (int off = 1; off < 1024; off <<= 1) {
        int tmp = (t >= off) ? sm[t - off] : 0;
        __syncthreads();
        sm[t] += tmp;
        __syncthreads();
    }
    if (t < NB) part[t] = sm[t] - v;   // exclusive
}

// phase 3: local exclusive scan + block offset, write rowptr & cursor
__global__ __launch_bounds__(256) void scan_final(const int* __restrict__ deg,
                                                  const int* __restrict__ part,
                                                  int* __restrict__ rowptr,
                                                  int* __restrict__ cursor, int N) {
    __shared__ int sm[256];
    int t = threadIdx.x;
    int base = blockIdx.x * 1024 + t * 4;
    int v0 = 0, v1 = 0, v2 = 0, v3 = 0;
    if (base + 4 <= N) {
        int4 v = *(const int4*)(deg + base);
        v0 = v.x; v1 = v.y; v2 = v.z; v3 = v.w;
    } else {
        if (base + 0 < N) v0 = deg[base + 0];
        if (base + 1 < N) v1 = deg[base + 1];
        if (base + 2 < N) v2 = deg[base + 2];
        if (base + 3 < N) v3 = deg[base + 3];
    }
    int s = v0 + v1 + v2 + v3;
    sm[t] = s;
    __syncthreads();
    for (int off = 1; off < 256; off <<= 1) {
        int tmp = (t >= off) ? sm[t - off] : 0;
        __syncthreads();
        sm[t] += tmp;
        __syncthreads();
    }
    int run = part[blockIdx.x] + sm[t] - s;   // exclusive prefix for this thread
    int r0 = run, r1 = r0 + v0, r2 = r1 + v1, r3 = r2 + v2;
    if (base + 4 <= N) {
        *(int4*)(rowptr + base) = (int4){r0, r1, r2, r3};
        *(int4*)(cursor + base) = (int4){r0, r1, r2, r3};
    } else {
        if (base + 0 < N) { rowptr[base + 0] = r0; cursor[base + 0] = r0; }
        if (base + 1 < N) { rowptr[base + 1] = r1; cursor[base + 1] = r1; }
        if (base + 2 < N) { rowptr[base + 2] = r2; cursor[base + 2] = r2; }
        if (base + 3 < N) { rowptr[base + 3] = r3; cursor[base + 3] = r3; }
    }
}

// fill CSR: csr_src[slot] = src id, slots allocated per-dst via cursor atomics
__global__ __launch_bounds__(256) void fill_csr(const int* __restrict__ ei,
                                                int* __restrict__ cursor,
                                                int* __restrict__ csr_src, int E) {
    int e = blockIdx.x * 256 + threadIdx.x;
    if (e >= E) return;
    int s = ei[e], d = ei[E + e];
    int slot = atomicAdd(cursor + d, 1);
    csr_src[slot] = s;
}

// one wave per dst: online-softmax gather, UNROLL-2 (independent even/odd
// states merged at the end -> 2 xh rows in flight). Emits out row + packed
// per-dst {a_dst, m, 1/(l+eps)} (12 floats) for att_edge.
__global__ __launch_bounds__(256) void gat_gather(const int* __restrict__ csr_src,
                                                  const int* __restrict__ rowptr,
                                                  const int* __restrict__ deg,
                                                  const float* __restrict__ a_src,
                                                  const float* __restrict__ a_dst,
                                                  const unsigned short* __restrict__ xh_bf,
                                                  float* __restrict__ out,
                                                  float* __restrict__ pack, int N) {
    int wave = threadIdx.x >> 6, lane = threadIdx.x & 63;
    int d = blockIdx.x * 4 + wave;
    if (d >= N) return;
    int h = lane >> 4;
    int start = rowptr[d], cnt = deg[d];
    float adst = a_dst[(size_t)d * 4 + h];

    if (cnt == 0) {
        *(float4v*)(out + (size_t)d * HC + lane * 4) = (float4v){0.f, 0.f, 0.f, 0.f};
        if ((lane & 15) == 0) {   // write pack anyway: no poison ever readable
            pack[(size_t)d * 12 + h]     = adst;
            pack[(size_t)d * 12 + 4 + h] = 0.f;
            pack[(size_t)d * 12 + 8 + h] = 0.f;
        }
        return;
    }

    float mE = -INFINITY, lE = 0.f, mO = -INFINITY, lO = 0.f;
    float4v accE = {0.f, 0.f, 0.f, 0.f}, accO = {0.f, 0.f, 0.f, 0.f};

    int s2 = 0, s3 = 0;
    float asE = 0.f, asO = 0.f;
    short4v xvE = {}, xvO = {};
    {
        int s0 = csr_src[start];
        asE = a_src[(size_t)s0 * 4 + h];
        xvE = *(const short4v*)(xh_bf + (size_t)s0 * HC + lane * 4);
    }
    if (cnt > 1) {
        int s1 = csr_src[start + 1];
        asO = a_src[(size_t)s1 * 4 + h];
        xvO = *(const short4v*)(xh_bf + (size_t)s1 * HC + lane * 4);
    }
    if (cnt > 2) s2 = csr_src[start + 2];
    if (cnt > 3) s3 = csr_src[start + 3];

    for (int i = 0; i < cnt; i += 2) {
        // prefetch data for edges i+2,i+3; ids for i+4,i+5
        float asE_n = 0.f, asO_n = 0.f;
        short4v xvE_n = {}, xvO_n = {};
        if (i + 2 < cnt) {
            asE_n = a_src[(size_t)s2 * 4 + h];
            xvE_n = *(const short4v*)(xh_bf + (size_t)s2 * HC + lane * 4);
        }
        if (i + 3 < cnt) {
            asO_n = a_src[(size_t)s3 * 4 + h];
            xvO_n = *(const short4v*)(xh_bf + (size_t)s3 * HC + lane * 4);
        }
        int s4 = (i + 4 < cnt) ? csr_src[start + i + 4] : 0;
        int s5 = (i + 5 < cnt) ? csr_src[start + i + 5] : 0;
        // compute edge i (E state)
        {
            float al = lrelu(asE + adst);
            float mn = fmaxf(mE, al);
            float sc = __expf(mE - mn);
            float p  = __expf(al - mn);
            lE = lE * sc + p;
#pragma unroll
            for (int j = 0; j < 4; ++j)
                accE[j] = accE[j] * sc + p * bf2f((unsigned short)xvE[j]);
            mE = mn;
        }
        // compute edge i+1 (O state)
        if (i + 1 < cnt) {
            float al = lrelu(asO + adst);
            float mn = fmaxf(mO, al);
            float sc = __expf(mO - mn);
            float p  = __expf(al - mn);
            lO = lO * sc + p;
#pragma unroll
            for (int j = 0; j < 4; ++j)
                accO[j] = accO[j] * sc + p * bf2f((unsigned short)xvO[j]);
            mO = mn;
        }
        asE = asE_n; xvE = xvE_n; asO = asO_n; xvO = xvO_n;
        s2 = s4; s3 = s5;
    }
    // merge states (mE finite since cnt >= 1; empty O contributes 0)
    float mm = fmaxf(mE, mO);
    float sE = __expf(mE - mm), sO = __expf(mO - mm);
    float l  = lE * sE + lO * sO;
    float inv = 1.f / (l + 1e-16f);
    float4v o;
#pragma unroll
    for (int j = 0; j < 4; ++j) o[j] = (accE[j] * sE + accO[j] * sO) * inv;
    *(float4v*)(out + (size_t)d * HC + lane * 4) = o;
    if ((lane & 15) == 0) {
        pack[(size_t)d * 12 + h]     = adst;
        pack[(size_t)d * 12 + 4 + h] = mm;
        pack[(size_t)d * 12 + 8 + h] = inv;
    }
}

// att[e,:] = exp(lrelu(a_src[s]+a_dst[d]) - m[d]) * inv_l[d]; packed dst reads
__global__ __launch_bounds__(256) void att_edge(const int* __restrict__ ei,
                                                const float* __restrict__ a_src,
                                                const float* __restrict__ pack,
                                                float* __restrict__ att_out, int E) {
    int e = blockIdx.x * 256 + threadIdx.x;
    if (e >= E) return;
    int s = ei[e], d = ei[E + e];
    float4v as = *(const float4v*)(a_src + (size_t)s * 4);
    float4v ad = *(const float4v*)(pack + (size_t)d * 12);
    float4v mm = *(const float4v*)(pack + (size_t)d * 12 + 4);
    float4v gg = *(const float4v*)(pack + (size_t)d * 12 + 8);
    float4v o;
#pragma unroll
    for (int h = 0; h < 4; ++h)
        o[h] = __expf(lrelu(as[h] + ad[h]) - mm[h]) * gg[h];
    *(float4v*)(att_out + (size_t)e * 4) = o;
}

// ---------------- launcher ----------------
extern "C" void kernel_launch(void* const* d_in, const int* in_sizes, int n_in,
                              void* d_out, int out_size, void* d_ws, size_t ws_size,
                              hipStream_t stream) {
    const float* x     = (const float*)d_in[0];  // fp32 [N,256]
    const int*   ei    = (const int*)d_in[1];    // int32 [2,E]
    const float* W     = (const float*)d_in[2];  // fp32 [256,256]
    const float* att_s = (const float*)d_in[3];  // fp32 [4,64]
    const float* att_d = (const float*)d_in[4];  // fp32 [4,64]

    const int N = in_sizes[0] / IN_CH;   // 50000
    const int E = in_sizes[1] / 2;       // 800000

    char* ws = (char*)d_ws;
    size_t off = 0;
    unsigned short* xh_bf = (unsigned short*)(ws + off); off += (size_t)N * HC * 2;
    unsigned short* x_hi  = (unsigned short*)(ws + off); off += (size_t)N * IN_CH * 2;
    unsigned short* x_lo  = (unsigned short*)(ws + off); off += (size_t)N * IN_CH * 2;
    unsigned short* wt    = (unsigned short*)(ws + off); off += (size_t)IN_CH * HC * 2;
    float* a_src = (float*)(ws + off); off += (size_t)N * H_HEADS * 4;
    float* a_dst = (float*)(ws + off); off += (size_t)N * H_HEADS * 4;
    float* pack  = (float*)(ws + off); off += (size_t)N * 12 * 4;
    int* rowptr  = (int*)(ws + off); off += (size_t)N * 4;
    int* cursor  = (int*)(ws + off); off += (size_t)N * 4;
    int* csr_src = (int*)(ws + off); off += (size_t)E * 4;
    int* part    = (int*)(ws + off); off += 1024 * 4;   // scan partials (NB<=1024)
    size_t zoff = off;  // zero-init region
    int* deg     = (int*)(ws + off); off += (size_t)N * 4;

    float* out     = (float*)d_out;            // [N, 256] fp32
    float* out_att = out + (size_t)N * HC;     // [E, 4]   fp32

    hipMemsetAsync(ws + zoff, 0, off - zoff, stream);  // deg only

    const int NB = (N + 1023) / 1024;          // scan blocks (49 for N=50000)

    prep_w<<<256, 256, 0, stream>>>(W, wt);
    prep_x<<<(N * IN_CH / 4 + 255) / 256, 256, 0, stream>>>(x, x_hi, x_lo, N * IN_CH / 4);
    deg_count<<<(E + 255) / 256, 256, 0, stream>>>(ei, deg, E);
    gemm_xh<<<(N + 15) / 16, 256, 0, stream>>>(x_hi, x_lo, wt, att_s, att_d,
                                               xh_bf, a_src, a_dst, N);
    scan_part<<<NB, 256, 0, stream>>>(deg, part, N);
    scan_mid<<<1, 1024, 0, stream>>>(part, NB);
    scan_final<<<NB, 256, 0, stream>>>(deg, part, rowptr, cursor, N);
    fill_csr<<<(E + 255) / 256, 256, 0, stream>>>(ei, cursor, csr_src, E);
    gat_gather<<<(N + 3) / 4, 256, 0, stream>>>(csr_src, rowptr, deg, a_src, a_dst,
                                                xh_bf, out, pack, N);
    att_edge<<<(E + 255) / 256, 256, 0, stream>>>(ei, a_src, pack, out_att, E);
}

// Round 4
// 332.104 us; speedup vs baseline: 1.3500x; 1.0473x over previous
//
#include <hip/hip_runtime.h>
#include <math.h>

// ---------------- constants (shapes fixed by the reference) ----------------
#define IN_CH   256
#define HC      256   // H*C
#define H_HEADS 4
#define NEG_SLOPE 0.2f
#define LOG2E   1.44269504088896f
#define DEFER_THR 12.0f   // base-2 defer-max threshold (2^12 = 4096, fp32-safe)

typedef __attribute__((ext_vector_type(8))) short short8;
typedef __attribute__((ext_vector_type(4))) short short4v;
typedef __attribute__((ext_vector_type(4))) float float4v;

// ---------------- helpers ----------------
__device__ __forceinline__ float bf2f(unsigned short b) {
    return __uint_as_float(((unsigned)b) << 16);
}
__device__ __forceinline__ unsigned short f2bf(float f) {
    unsigned u = __float_as_uint(f);
    u += 0x7fffu + ((u >> 16) & 1u);    // round-to-nearest-even
    return (unsigned short)(u >> 16);
}
__device__ __forceinline__ float lrelu(float a) {
    return a >= 0.f ? a : NEG_SLOPE * a;
}
// base-2 exp: single v_exp_f32 (natively 2^x on gfx950).
// NB: "__exp2f" spelling collides with glibc math.h macros — use the builtin.
__device__ __forceinline__ float fexp2(float a) {
    return __builtin_amdgcn_exp2f(a);
}

// ---------------- kernels ----------------

// W (fp32, [256k x 256c] row-major) -> transposed bf16 (wt[c][k])
__global__ void prep_w(const float* __restrict__ w,
                       unsigned short* __restrict__ wt) {
    int idx = blockIdx.x * 256 + threadIdx.x;   // 65536 total
    int k = idx >> 8, c = idx & 255;
    wt[(size_t)c * 256 + k] = f2bf(w[idx]);
}

// xh = x @ W. Block = 16 rows x 256 cols (4 waves = 4 heads).
// Stages fp32 x directly; bf16 hi/lo split done in-register during staging
// (prep_x kernel fused away: saves 102 MB of HBM round-trip).
// Chunk-transposed LDS layout [kc][m]; hi slots at [0,8K), lo at [8K,16K).
// Epilogue fuses node_attn; att vectors pre-scaled by LOG2E so all logits
// live in base-2 domain (consumers use exp2).
__global__ __launch_bounds__(256) void gemm_xh(const float* __restrict__ x,
                                               const unsigned short* __restrict__ wt,
                                               const float* __restrict__ att_s,
                                               const float* __restrict__ att_d,
                                               unsigned short* __restrict__ xh_bf,
                                               float* __restrict__ a_src,
                                               float* __restrict__ a_dst, int N) {
    __shared__ __attribute__((aligned(16))) unsigned char lds_a[16384];
    int tid  = threadIdx.x;
    int wave = tid >> 6;            // == head index
    int lane = tid & 63;
    int quad = lane >> 4;
    int l16  = lane & 15;
    int rb   = blockIdx.x * 16;

    // ---- stage A-tile: 512 chunks x 8 floats -> hi/lo short8 slots ----
#pragma unroll
    for (int pass = 0; pass < 2; ++pass) {
        int s  = pass * 256 + tid;              // 0..511
        int kc = s >> 4;                        // 16-B chunk index (k/8)
        int m  = s & 15;                        // row within tile
        int grow = rb + m; if (grow >= N) grow = N - 1;
        const float* gp = x + (size_t)grow * IN_CH + kc * 8;
        float4v f0 = *(const float4v*)gp;
        float4v f1 = *(const float4v*)(gp + 4);
        short8 hi, lo;
#pragma unroll
        for (int j = 0; j < 4; ++j) {
            unsigned short h0 = f2bf(f0[j]);
            hi[j] = (short)h0;
            lo[j] = (short)f2bf(f0[j] - bf2f(h0));
            unsigned short h1 = f2bf(f1[j]);
            hi[4 + j] = (short)h1;
            lo[4 + j] = (short)f2bf(f1[j] - bf2f(h1));
        }
        *(short8*)(lds_a + (size_t)s * 16) = hi;
        *(short8*)(lds_a + 8192 + (size_t)s * 16) = lo;
    }
    __syncthreads();

    // ---- K-loop: 8 x { 2 ds_read_b128 + 4 x (1 B-load + 2 MFMA) } ----
    float4v acc[4] = {};
    const unsigned short* wt_base = wt + ((size_t)wave * 64 + l16) * IN_CH;
#pragma unroll
    for (int k0 = 0; k0 < 8; ++k0) {
        int kc   = k0 * 4 + quad;
        int slot = kc * 16 + l16;
        short8 a_hi = *(const short8*)(lds_a + slot * 16);
        short8 a_lo = *(const short8*)(lds_a + 8192 + slot * 16);
#pragma unroll
        for (int ct = 0; ct < 4; ++ct) {
            short8 bh = *(const short8*)(wt_base + (size_t)ct * 16 * IN_CH
                                         + k0 * 32 + quad * 8);
            acc[ct] = __builtin_amdgcn_mfma_f32_16x16x32_bf16(a_lo, bh, acc[ct], 0, 0, 0);
            acc[ct] = __builtin_amdgcn_mfma_f32_16x16x32_bf16(a_hi, bh, acc[ct], 0, 0, 0);
        }
    }

    // ---- epilogue: xh store + fused a_src/a_dst (head = wave, base-2) ----
    int cb = wave;
    float ps[4] = {0.f, 0.f, 0.f, 0.f};
    float pd[4] = {0.f, 0.f, 0.f, 0.f};
#pragma unroll
    for (int ct = 0; ct < 4; ++ct) {
        float as_c = att_s[cb * 64 + ct * 16 + l16] * LOG2E;
        float ad_c = att_d[cb * 64 + ct * 16 + l16] * LOG2E;
#pragma unroll
        for (int r = 0; r < 4; ++r) {
            float v = acc[ct][r];
            int grow = rb + quad * 4 + r;
            if (grow < N)
                xh_bf[(size_t)grow * HC + cb * 64 + ct * 16 + l16] = f2bf(v);
            ps[r] += v * as_c;
            pd[r] += v * ad_c;
        }
    }
#pragma unroll
    for (int off = 1; off < 16; off <<= 1) {
#pragma unroll
        for (int r = 0; r < 4; ++r) {
            ps[r] += __shfl_xor(ps[r], off);
            pd[r] += __shfl_xor(pd[r], off);
        }
    }
    if (l16 == 0) {
#pragma unroll
        for (int r = 0; r < 4; ++r) {
            int grow = rb + quad * 4 + r;
            if (grow < N) {
                a_src[(size_t)grow * 4 + cb] = ps[r];
                a_dst[(size_t)grow * 4 + cb] = pd[r];
            }
        }
    }
}

// degree histogram over dst
__global__ __launch_bounds__(256) void deg_count(const int* __restrict__ ei,
                                                 int* __restrict__ deg, int E) {
    int e = blockIdx.x * 256 + threadIdx.x;
    if (e >= E) return;
    atomicAdd(deg + ei[E + e], 1);
}

// ---- device-wide exclusive scan of deg[N] -> rowptr, cursor (2 phases) ----

// phase 1: per-block sums (1024 elements / block)
__global__ __launch_bounds__(256) void scan_part(const int* __restrict__ deg,
                                                 int* __restrict__ part, int N) {
    int t = threadIdx.x;
    int base = blockIdx.x * 1024 + t * 4;
    int s = 0;
    if (base + 4 <= N) {
        int4 v = *(const int4*)(deg + base);
        s = v.x + v.y + v.z + v.w;
    } else {
#pragma unroll
        for (int j = 0; j < 4; ++j)
            if (base + j < N) s += deg[base + j];
    }
#pragma unroll
    for (int off = 1; off < 64; off <<= 1) s += __shfl_xor(s, off);
    __shared__ int ws[4];
    if ((t & 63) == 0) ws[t >> 6] = s;
    __syncthreads();
    if (t == 0) part[blockIdx.x] = ws[0] + ws[1] + ws[2] + ws[3];
}

// phase 2: block offset = sum(part[0..bid)) computed in-block (NB ~ 49),
// then local exclusive scan, write rowptr & cursor.
__global__ __launch_bounds__(256) void scan_final(const int* __restrict__ deg,
                                                  const int* __restrict__ part,
                                                  int* __restrict__ rowptr,
                                                  int* __restrict__ cursor, int N) {
    __shared__ int sm[256];
    __shared__ int wsum[4];
    int t = threadIdx.x;
    // block offset: strided sum of preceding partials, block-reduced
    int bacc = 0;
    for (int j = t; j < blockIdx.x; j += 256) bacc += part[j];
#pragma unroll
    for (int off = 1; off < 64; off <<= 1) bacc += __shfl_xor(bacc, off);
    if ((t & 63) == 0) wsum[t >> 6] = bacc;

    int base = blockIdx.x * 1024 + t * 4;
    int v0 = 0, v1 = 0, v2 = 0, v3 = 0;
    if (base + 4 <= N) {
        int4 v = *(const int4*)(deg + base);
        v0 = v.x; v1 = v.y; v2 = v.z; v3 = v.w;
    } else {
        if (base + 0 < N) v0 = deg[base + 0];
        if (base + 1 < N) v1 = deg[base + 1];
        if (base + 2 < N) v2 = deg[base + 2];
        if (base + 3 < N) v3 = deg[base + 3];
    }
    int s = v0 + v1 + v2 + v3;
    sm[t] = s;
    __syncthreads();
    for (int off = 1; off < 256; off <<= 1) {
        int tmp = (t >= off) ? sm[t - off] : 0;
        __syncthreads();
        sm[t] += tmp;
        __syncthreads();
    }
    int boff = wsum[0] + wsum[1] + wsum[2] + wsum[3];
    int run = boff + sm[t] - s;   // exclusive prefix for this thread
    int r0 = run, r1 = r0 + v0, r2 = r1 + v1, r3 = r2 + v2;
    if (base + 4 <= N) {
        *(int4*)(rowptr + base) = (int4){r0, r1, r2, r3};
        *(int4*)(cursor + base) = (int4){r0, r1, r2, r3};
    } else {
        if (base + 0 < N) { rowptr[base + 0] = r0; cursor[base + 0] = r0; }
        if (base + 1 < N) { rowptr[base + 1] = r1; cursor[base + 1] = r1; }
        if (base + 2 < N) { rowptr[base + 2] = r2; cursor[base + 2] = r2; }
        if (base + 3 < N) { rowptr[base + 3] = r3; cursor[base + 3] = r3; }
    }
}

// fill CSR: csr_src[slot] = src id, slots allocated per-dst via cursor atomics
__global__ __launch_bounds__(256) void fill_csr(const int* __restrict__ ei,
                                                int* __restrict__ cursor,
                                                int* __restrict__ csr_src, int E) {
    int e = blockIdx.x * 256 + threadIdx.x;
    if (e >= E) return;
    int s = ei[e], d = ei[E + e];
    int slot = atomicAdd(cursor + d, 1);
    csr_src[slot] = s;
}

// one wave per dst: online-softmax gather in base-2 domain, UNROLL-2 with
// defer-max (T13): wave-uniform fast path skips the rescale while
// al <= m + DEFER_THR (normalization is invariant to the stale max).
// Emits out row + packed per-dst {a_dst2, m2, 1/(l+eps)} for att_edge.
__global__ __launch_bounds__(256) void gat_gather(const int* __restrict__ csr_src,
                                                  const int* __restrict__ rowptr,
                                                  const int* __restrict__ deg,
                                                  const float* __restrict__ a_src,
                                                  const float* __restrict__ a_dst,
                                                  const unsigned short* __restrict__ xh_bf,
                                                  float* __restrict__ out,
                                                  float* __restrict__ pack, int N) {
    int wave = threadIdx.x >> 6, lane = threadIdx.x & 63;
    int d = blockIdx.x * 4 + wave;
    if (d >= N) return;
    int h = lane >> 4;
    int start = rowptr[d], cnt = deg[d];
    float adst = a_dst[(size_t)d * 4 + h];

    if (cnt == 0) {
        *(float4v*)(out + (size_t)d * HC + lane * 4) = (float4v){0.f, 0.f, 0.f, 0.f};
        if ((lane & 15) == 0) {   // write pack anyway: no poison ever readable
            pack[(size_t)d * 12 + h]     = adst;
            pack[(size_t)d * 12 + 4 + h] = 0.f;
            pack[(size_t)d * 12 + 8 + h] = 0.f;
        }
        return;
    }

    float mE = -INFINITY, lE = 0.f, mO = -INFINITY, lO = 0.f;
    float4v accE = {0.f, 0.f, 0.f, 0.f}, accO = {0.f, 0.f, 0.f, 0.f};

    int s2 = 0, s3 = 0;
    float asE = 0.f, asO = 0.f;
    short4v xvE = {}, xvO = {};
    {
        int s0 = csr_src[start];
        asE = a_src[(size_t)s0 * 4 + h];
        xvE = *(const short4v*)(xh_bf + (size_t)s0 * HC + lane * 4);
    }
    if (cnt > 1) {
        int s1 = csr_src[start + 1];
        asO = a_src[(size_t)s1 * 4 + h];
        xvO = *(const short4v*)(xh_bf + (size_t)s1 * HC + lane * 4);
    }
    if (cnt > 2) s2 = csr_src[start + 2];
    if (cnt > 3) s3 = csr_src[start + 3];

    for (int i = 0; i < cnt; i += 2) {
        // prefetch data for edges i+2,i+3; ids for i+4,i+5
        float asE_n = 0.f, asO_n = 0.f;
        short4v xvE_n = {}, xvO_n = {};
        if (i + 2 < cnt) {
            asE_n = a_src[(size_t)s2 * 4 + h];
            xvE_n = *(const short4v*)(xh_bf + (size_t)s2 * HC + lane * 4);
        }
        if (i + 3 < cnt) {
            asO_n = a_src[(size_t)s3 * 4 + h];
            xvO_n = *(const short4v*)(xh_bf + (size_t)s3 * HC + lane * 4);
        }
        int s4 = (i + 4 < cnt) ? csr_src[start + i + 4] : 0;
        int s5 = (i + 5 < cnt) ? csr_src[start + i + 5] : 0;

        bool haveO = (i + 1 < cnt);            // wave-uniform
        float alE = lrelu(asE + adst);
        bool ok = (alE <= mE + DEFER_THR);
        float alO = 0.f;
        if (haveO) {
            alO = lrelu(asO + adst);
            ok = ok && (alO <= mO + DEFER_THR);
        }
        if (__all(ok)) {
            // fast path: stale max, no rescale
            float p = fexp2(alE - mE);
            lE += p;
#pragma unroll
            for (int j = 0; j < 4; ++j)
                accE[j] += p * bf2f((unsigned short)xvE[j]);
            if (haveO) {
                float q = fexp2(alO - mO);
                lO += q;
#pragma unroll
                for (int j = 0; j < 4; ++j)
                    accO[j] += q * bf2f((unsigned short)xvO[j]);
            }
        } else {
            // slow path: classic online-softmax rescale
            {
                float mn = fmaxf(mE, alE);
                float sc = fexp2(mE - mn);
                float p  = fexp2(alE - mn);
                lE = lE * sc + p;
#pragma unroll
                for (int j = 0; j < 4; ++j)
                    accE[j] = accE[j] * sc + p * bf2f((unsigned short)xvE[j]);
                mE = mn;
            }
            if (haveO) {
                float mn = fmaxf(mO, alO);
                float sc = fexp2(mO - mn);
                float p  = fexp2(alO - mn);
                lO = lO * sc + p;
#pragma unroll
                for (int j = 0; j < 4; ++j)
                    accO[j] = accO[j] * sc + p * bf2f((unsigned short)xvO[j]);
                mO = mn;
            }
        }
        asE = asE_n; xvE = xvE_n; asO = asO_n; xvO = xvO_n;
        s2 = s4; s3 = s5;
    }
    // merge states on their (possibly stale) maxes — exact regardless
    float mm = fmaxf(mE, mO);
    float sE = fexp2(mE - mm), sO = fexp2(mO - mm);
    float l  = lE * sE + lO * sO;
    float inv = 1.f / (l + 1e-16f);
    float4v o;
#pragma unroll
    for (int j = 0; j < 4; ++j) o[j] = (accE[j] * sE + accO[j] * sO) * inv;
    *(float4v*)(out + (size_t)d * HC + lane * 4) = o;
    if ((lane & 15) == 0) {
        pack[(size_t)d * 12 + h]     = adst;
        pack[(size_t)d * 12 + 4 + h] = mm;
        pack[(size_t)d * 12 + 8 + h] = inv;
    }
}

// att[e,:] = exp2(lrelu(as2+ad2) - m2[d]) * inv_l[d]; packed dst reads
__global__ __launch_bounds__(256) void att_edge(const int* __restrict__ ei,
                                                const float* __restrict__ a_src,
                                                const float* __restrict__ pack,
                                                float* __restrict__ att_out, int E) {
    int e = blockIdx.x * 256 + threadIdx.x;
    if (e >= E) return;
    int s = ei[e], d = ei[E + e];
    float4v as = *(const float4v*)(a_src + (size_t)s * 4);
    float4v ad = *(const float4v*)(pack + (size_t)d * 12);
    float4v mm = *(const float4v*)(pack + (size_t)d * 12 + 4);
    float4v gg = *(const float4v*)(pack + (size_t)d * 12 + 8);
    float4v o;
#pragma unroll
    for (int h = 0; h < 4; ++h)
        o[h] = fexp2(lrelu(as[h] + ad[h]) - mm[h]) * gg[h];
    *(float4v*)(att_out + (size_t)e * 4) = o;
}

// ---------------- launcher ----------------
extern "C" void kernel_launch(void* const* d_in, const int* in_sizes, int n_in,
                              void* d_out, int out_size, void* d_ws, size_t ws_size,
                              hipStream_t stream) {
    const float* x     = (const float*)d_in[0];  // fp32 [N,256]
    const int*   ei    = (const int*)d_in[1];    // int32 [2,E]
    const float* W     = (const float*)d_in[2];  // fp32 [256,256]
    const float* att_s = (const float*)d_in[3];  // fp32 [4,64]
    const float* att_d = (const float*)d_in[4];  // fp32 [4,64]

    const int N = in_sizes[0] / IN_CH;   // 50000
    const int E = in_sizes[1] / 2;       // 800000

    char* ws = (char*)d_ws;
    size_t off = 0;
    unsigned short* xh_bf = (unsigned short*)(ws + off); off += (size_t)N * HC * 2;
    unsigned short* wt    = (unsigned short*)(ws + off); off += (size_t)IN_CH * HC * 2;
    float* a_src = (float*)(ws + off); off += (size_t)N * H_HEADS * 4;
    float* a_dst = (float*)(ws + off); off += (size_t)N * H_HEADS * 4;
    float* pack  = (float*)(ws + off); off += (size_t)N * 12 * 4;
    int* rowptr  = (int*)(ws + off); off += (size_t)N * 4;
    int* cursor  = (int*)(ws + off); off += (size_t)N * 4;
    int* csr_src = (int*)(ws + off); off += (size_t)E * 4;
    int* part    = (int*)(ws + off); off += 1024 * 4;   // scan partials (NB<=1024)
    size_t zoff = off;  // zero-init region
    int* deg     = (int*)(ws + off); off += (size_t)N * 4;

    float* out     = (float*)d_out;            // [N, 256] fp32
    float* out_att = out + (size_t)N * HC;     // [E, 4]   fp32

    (void)hipMemsetAsync(ws + zoff, 0, off - zoff, stream);  // deg only

    const int NB = (N + 1023) / 1024;          // scan blocks (49 for N=50000)

    prep_w<<<256, 256, 0, stream>>>(W, wt);
    deg_count<<<(E + 255) / 256, 256, 0, stream>>>(ei, deg, E);
    gemm_xh<<<(N + 15) / 16, 256, 0, stream>>>(x, wt, att_s, att_d,
                                               xh_bf, a_src, a_dst, N);
    scan_part<<<NB, 256, 0, stream>>>(deg, part, N);
    scan_final<<<NB, 256, 0, stream>>>(deg, part, rowptr, cursor, N);
    fill_csr<<<(E + 255) / 256, 256, 0, stream>>>(ei, cursor, csr_src, E);
    gat_gather<<<(N + 3) / 4, 256, 0, stream>>>(csr_src, rowptr, deg, a_src, a_dst,
                                                xh_bf, out, pack, N);
    att_edge<<<(E + 255) / 256, 256, 0, stream>>>(ei, a_src, pack, out_att, E);
}

// Round 5
// 324.167 us; speedup vs baseline: 1.3830x; 1.0245x over previous
//
#include <hip/hip_runtime.h>
#include <math.h>

// ---------------- constants (shapes fixed by the reference) ----------------
#define IN_CH   256
#define HC      256   // H*C
#define H_HEADS 4
#define NEG_SLOPE 0.2f
#define LOG2E   1.44269504088896f
#define DEFER_THR 12.0f   // base-2 defer-max threshold (2^12 = 4096, fp32-safe)

typedef __attribute__((ext_vector_type(8))) short short8;
typedef __attribute__((ext_vector_type(4))) short short4v;
typedef __attribute__((ext_vector_type(4))) float float4v;

// ---------------- helpers ----------------
__device__ __forceinline__ float bf2f(unsigned short b) {
    return __uint_as_float(((unsigned)b) << 16);
}
__device__ __forceinline__ unsigned short f2bf(float f) {
    unsigned u = __float_as_uint(f);
    u += 0x7fffu + ((u >> 16) & 1u);    // round-to-nearest-even
    return (unsigned short)(u >> 16);
}
__device__ __forceinline__ float lrelu(float a) {
    return a >= 0.f ? a : NEG_SLOPE * a;
}
// base-2 exp: single v_exp_f32 (natively 2^x on gfx950).
__device__ __forceinline__ float fexp2(float a) {
    return __builtin_amdgcn_exp2f(a);
}

// ---------------- kernels ----------------

// W (fp32, [256k x 256c] row-major) -> transposed bf16 (wt[c][k])
__global__ void prep_w(const float* __restrict__ w,
                       unsigned short* __restrict__ wt) {
    int idx = blockIdx.x * 256 + threadIdx.x;   // 65536 total
    int k = idx >> 8, c = idx & 255;
    wt[(size_t)c * 256 + k] = f2bf(w[idx]);
}

// xh = x @ W. Block = 16 rows x 256 cols (4 waves = 4 heads).
// Stages fp32 x directly; bf16 hi/lo split done in-register during staging.
// Epilogue fuses node_attn; att vectors pre-scaled by LOG2E so all logits
// live in base-2 domain (consumers use exp2).
__global__ __launch_bounds__(256) void gemm_xh(const float* __restrict__ x,
                                               const unsigned short* __restrict__ wt,
                                               const float* __restrict__ att_s,
                                               const float* __restrict__ att_d,
                                               unsigned short* __restrict__ xh_bf,
                                               float* __restrict__ a_src,
                                               float* __restrict__ a_dst, int N) {
    __shared__ __attribute__((aligned(16))) unsigned char lds_a[16384];
    int tid  = threadIdx.x;
    int wave = tid >> 6;            // == head index
    int lane = tid & 63;
    int quad = lane >> 4;
    int l16  = lane & 15;
    int rb   = blockIdx.x * 16;

    // ---- stage A-tile: 512 chunks x 8 floats -> hi/lo short8 slots ----
#pragma unroll
    for (int pass = 0; pass < 2; ++pass) {
        int s  = pass * 256 + tid;              // 0..511
        int kc = s >> 4;                        // 16-B chunk index (k/8)
        int m  = s & 15;                        // row within tile
        int grow = rb + m; if (grow >= N) grow = N - 1;
        const float* gp = x + (size_t)grow * IN_CH + kc * 8;
        float4v f0 = *(const float4v*)gp;
        float4v f1 = *(const float4v*)(gp + 4);
        short8 hi, lo;
#pragma unroll
        for (int j = 0; j < 4; ++j) {
            unsigned short h0 = f2bf(f0[j]);
            hi[j] = (short)h0;
            lo[j] = (short)f2bf(f0[j] - bf2f(h0));
            unsigned short h1 = f2bf(f1[j]);
            hi[4 + j] = (short)h1;
            lo[4 + j] = (short)f2bf(f1[j] - bf2f(h1));
        }
        *(short8*)(lds_a + (size_t)s * 16) = hi;
        *(short8*)(lds_a + 8192 + (size_t)s * 16) = lo;
    }
    __syncthreads();

    // ---- K-loop: 8 x { 2 ds_read_b128 + 4 x (1 B-load + 2 MFMA) } ----
    float4v acc[4] = {};
    const unsigned short* wt_base = wt + ((size_t)wave * 64 + l16) * IN_CH;
#pragma unroll
    for (int k0 = 0; k0 < 8; ++k0) {
        int kc   = k0 * 4 + quad;
        int slot = kc * 16 + l16;
        short8 a_hi = *(const short8*)(lds_a + slot * 16);
        short8 a_lo = *(const short8*)(lds_a + 8192 + slot * 16);
#pragma unroll
        for (int ct = 0; ct < 4; ++ct) {
            short8 bh = *(const short8*)(wt_base + (size_t)ct * 16 * IN_CH
                                         + k0 * 32 + quad * 8);
            acc[ct] = __builtin_amdgcn_mfma_f32_16x16x32_bf16(a_lo, bh, acc[ct], 0, 0, 0);
            acc[ct] = __builtin_amdgcn_mfma_f32_16x16x32_bf16(a_hi, bh, acc[ct], 0, 0, 0);
        }
    }

    // ---- epilogue: xh store + fused a_src/a_dst (head = wave, base-2) ----
    int cb = wave;
    float ps[4] = {0.f, 0.f, 0.f, 0.f};
    float pd[4] = {0.f, 0.f, 0.f, 0.f};
#pragma unroll
    for (int ct = 0; ct < 4; ++ct) {
        float as_c = att_s[cb * 64 + ct * 16 + l16] * LOG2E;
        float ad_c = att_d[cb * 64 + ct * 16 + l16] * LOG2E;
#pragma unroll
        for (int r = 0; r < 4; ++r) {
            float v = acc[ct][r];
            int grow = rb + quad * 4 + r;
            if (grow < N)
                xh_bf[(size_t)grow * HC + cb * 64 + ct * 16 + l16] = f2bf(v);
            ps[r] += v * as_c;
            pd[r] += v * ad_c;
        }
    }
#pragma unroll
    for (int off = 1; off < 16; off <<= 1) {
#pragma unroll
        for (int r = 0; r < 4; ++r) {
            ps[r] += __shfl_xor(ps[r], off);
            pd[r] += __shfl_xor(pd[r], off);
        }
    }
    if (l16 == 0) {
#pragma unroll
        for (int r = 0; r < 4; ++r) {
            int grow = rb + quad * 4 + r;
            if (grow < N) {
                a_src[(size_t)grow * 4 + cb] = ps[r];
                a_dst[(size_t)grow * 4 + cb] = pd[r];
            }
        }
    }
}

// degree histogram over dst
__global__ __launch_bounds__(256) void deg_count(const int* __restrict__ ei,
                                                 int* __restrict__ deg, int E) {
    int e = blockIdx.x * 256 + threadIdx.x;
    if (e >= E) return;
    atomicAdd(deg + ei[E + e], 1);
}

// ---- device-wide exclusive scan of deg[N] -> rowptr, cursor (2 phases) ----

// phase 1: per-block sums (1024 elements / block)
__global__ __launch_bounds__(256) void scan_part(const int* __restrict__ deg,
                                                 int* __restrict__ part, int N) {
    int t = threadIdx.x;
    int base = blockIdx.x * 1024 + t * 4;
    int s = 0;
    if (base + 4 <= N) {
        int4 v = *(const int4*)(deg + base);
        s = v.x + v.y + v.z + v.w;
    } else {
#pragma unroll
        for (int j = 0; j < 4; ++j)
            if (base + j < N) s += deg[base + j];
    }
#pragma unroll
    for (int off = 1; off < 64; off <<= 1) s += __shfl_xor(s, off);
    __shared__ int ws[4];
    if ((t & 63) == 0) ws[t >> 6] = s;
    __syncthreads();
    if (t == 0) part[blockIdx.x] = ws[0] + ws[1] + ws[2] + ws[3];
}

// phase 2: block offset = sum(part[0..bid)) computed in-block (NB ~ 49),
// then local exclusive scan, write rowptr & cursor.
__global__ __launch_bounds__(256) void scan_final(const int* __restrict__ deg,
                                                  const int* __restrict__ part,
                                                  int* __restrict__ rowptr,
                                                  int* __restrict__ cursor, int N) {
    __shared__ int sm[256];
    __shared__ int wsum[4];
    int t = threadIdx.x;
    int bacc = 0;
    for (int j = t; j < blockIdx.x; j += 256) bacc += part[j];
#pragma unroll
    for (int off = 1; off < 64; off <<= 1) bacc += __shfl_xor(bacc, off);
    if ((t & 63) == 0) wsum[t >> 6] = bacc;

    int base = blockIdx.x * 1024 + t * 4;
    int v0 = 0, v1 = 0, v2 = 0, v3 = 0;
    if (base + 4 <= N) {
        int4 v = *(const int4*)(deg + base);
        v0 = v.x; v1 = v.y; v2 = v.z; v3 = v.w;
    } else {
        if (base + 0 < N) v0 = deg[base + 0];
        if (base + 1 < N) v1 = deg[base + 1];
        if (base + 2 < N) v2 = deg[base + 2];
        if (base + 3 < N) v3 = deg[base + 3];
    }
    int s = v0 + v1 + v2 + v3;
    sm[t] = s;
    __syncthreads();
    for (int off = 1; off < 256; off <<= 1) {
        int tmp = (t >= off) ? sm[t - off] : 0;
        __syncthreads();
        sm[t] += tmp;
        __syncthreads();
    }
    int boff = wsum[0] + wsum[1] + wsum[2] + wsum[3];
    int run = boff + sm[t] - s;   // exclusive prefix for this thread
    int r0 = run, r1 = r0 + v0, r2 = r1 + v1, r3 = r2 + v2;
    if (base + 4 <= N) {
        *(int4*)(rowptr + base) = (int4){r0, r1, r2, r3};
        *(int4*)(cursor + base) = (int4){r0, r1, r2, r3};
    } else {
        if (base + 0 < N) { rowptr[base + 0] = r0; cursor[base + 0] = r0; }
        if (base + 1 < N) { rowptr[base + 1] = r1; cursor[base + 1] = r1; }
        if (base + 2 < N) { rowptr[base + 2] = r2; cursor[base + 2] = r2; }
        if (base + 3 < N) { rowptr[base + 3] = r3; cursor[base + 3] = r3; }
    }
}

// fill CSR + precompute per-edge logits (base-2, lrelu applied).
// Edge-parallel & latency-tolerant: absorbs the random a_src/a_dst gathers
// here so the latency-chained gat_gather loop doesn't have to.
// csr_al is slot-ordered (sequential reads in gat_gather);
// al_e is edge-ordered (sequential reads in att_edge).
__global__ __launch_bounds__(256) void fill_csr(const int* __restrict__ ei,
                                                const float* __restrict__ a_src,
                                                const float* __restrict__ a_dst,
                                                int* __restrict__ cursor,
                                                int* __restrict__ csr_src,
                                                float* __restrict__ csr_al,
                                                float* __restrict__ al_e, int E) {
    int e = blockIdx.x * 256 + threadIdx.x;
    if (e >= E) return;
    int s = ei[e], d = ei[E + e];
    float4v as = *(const float4v*)(a_src + (size_t)s * 4);
    float4v ad = *(const float4v*)(a_dst + (size_t)d * 4);
    float4v al;
#pragma unroll
    for (int h = 0; h < 4; ++h) al[h] = lrelu(as[h] + ad[h]);
    int slot = atomicAdd(cursor + d, 1);
    csr_src[slot] = s;
    *(float4v*)(csr_al + (size_t)slot * 4) = al;
    *(float4v*)(al_e + (size_t)e * 4) = al;
}

// one wave per dst: online-softmax gather in base-2 domain, UNROLL-2 with
// defer-max. Logits come precomputed from csr_al (sequential stream) —
// only xh remains a dependent random gather (1 hop/iter instead of 2).
// Emits out row + packed per-dst {m2[4], inv[4]} (8 floats) for att_edge.
__global__ __launch_bounds__(256) void gat_gather(const int* __restrict__ csr_src,
                                                  const float* __restrict__ csr_al,
                                                  const int* __restrict__ rowptr,
                                                  const int* __restrict__ deg,
                                                  const unsigned short* __restrict__ xh_bf,
                                                  float* __restrict__ out,
                                                  float* __restrict__ pack, int N) {
    int wave = threadIdx.x >> 6, lane = threadIdx.x & 63;
    int d = blockIdx.x * 4 + wave;
    if (d >= N) return;
    int h = lane >> 4;
    int start = rowptr[d], cnt = deg[d];

    if (cnt == 0) {
        *(float4v*)(out + (size_t)d * HC + lane * 4) = (float4v){0.f, 0.f, 0.f, 0.f};
        if ((lane & 15) == 0) {   // write pack anyway: no poison ever readable
            pack[(size_t)d * 8 + h]     = 0.f;
            pack[(size_t)d * 8 + 4 + h] = 0.f;
        }
        return;
    }

    float mE = -INFINITY, lE = 0.f, mO = -INFINITY, lO = 0.f;
    float4v accE = {0.f, 0.f, 0.f, 0.f}, accO = {0.f, 0.f, 0.f, 0.f};

    int s2 = 0, s3 = 0;
    float alE = 0.f, alO = 0.f;
    short4v xvE = {}, xvO = {};
    {
        int s0 = csr_src[start];
        alE = csr_al[(size_t)start * 4 + h];
        xvE = *(const short4v*)(xh_bf + (size_t)s0 * HC + lane * 4);
    }
    if (cnt > 1) {
        int s1 = csr_src[start + 1];
        alO = csr_al[(size_t)(start + 1) * 4 + h];
        xvO = *(const short4v*)(xh_bf + (size_t)s1 * HC + lane * 4);
    }
    if (cnt > 2) s2 = csr_src[start + 2];
    if (cnt > 3) s3 = csr_src[start + 3];

    for (int i = 0; i < cnt; i += 2) {
        // prefetch data for edges i+2,i+3; ids for i+4,i+5
        float alE_n = 0.f, alO_n = 0.f;
        short4v xvE_n = {}, xvO_n = {};
        if (i + 2 < cnt) {
            alE_n = csr_al[(size_t)(start + i + 2) * 4 + h];
            xvE_n = *(const short4v*)(xh_bf + (size_t)s2 * HC + lane * 4);
        }
        if (i + 3 < cnt) {
            alO_n = csr_al[(size_t)(start + i + 3) * 4 + h];
            xvO_n = *(const short4v*)(xh_bf + (size_t)s3 * HC + lane * 4);
        }
        int s4 = (i + 4 < cnt) ? csr_src[start + i + 4] : 0;
        int s5 = (i + 5 < cnt) ? csr_src[start + i + 5] : 0;

        bool haveO = (i + 1 < cnt);            // wave-uniform
        bool ok = (alE <= mE + DEFER_THR);
        if (haveO) ok = ok && (alO <= mO + DEFER_THR);
        if (__all(ok)) {
            // fast path: stale max, no rescale
            float p = fexp2(alE - mE);
            lE += p;
#pragma unroll
            for (int j = 0; j < 4; ++j)
                accE[j] += p * bf2f((unsigned short)xvE[j]);
            if (haveO) {
                float q = fexp2(alO - mO);
                lO += q;
#pragma unroll
                for (int j = 0; j < 4; ++j)
                    accO[j] += q * bf2f((unsigned short)xvO[j]);
            }
        } else {
            // slow path: classic online-softmax rescale
            {
                float mn = fmaxf(mE, alE);
                float sc = fexp2(mE - mn);
                float p  = fexp2(alE - mn);
                lE = lE * sc + p;
#pragma unroll
                for (int j = 0; j < 4; ++j)
                    accE[j] = accE[j] * sc + p * bf2f((unsigned short)xvE[j]);
                mE = mn;
            }
            if (haveO) {
                float mn = fmaxf(mO, alO);
                float sc = fexp2(mO - mn);
                float p  = fexp2(alO - mn);
                lO = lO * sc + p;
#pragma unroll
                for (int j = 0; j < 4; ++j)
                    accO[j] = accO[j] * sc + p * bf2f((unsigned short)xvO[j]);
                mO = mn;
            }
        }
        alE = alE_n; xvE = xvE_n; alO = alO_n; xvO = xvO_n;
        s2 = s4; s3 = s5;
    }
    // merge states on their (possibly stale) maxes — exact regardless
    float mm = fmaxf(mE, mO);
    float sE = fexp2(mE - mm), sO = fexp2(mO - mm);
    float l  = lE * sE + lO * sO;
    float inv = 1.f / (l + 1e-16f);
    float4v o;
#pragma unroll
    for (int j = 0; j < 4; ++j) o[j] = (accE[j] * sE + accO[j] * sO) * inv;
    *(float4v*)(out + (size_t)d * HC + lane * 4) = o;
    if ((lane & 15) == 0) {
        pack[(size_t)d * 8 + h]     = mm;
        pack[(size_t)d * 8 + 4 + h] = inv;
    }
}

// att[e,:] = exp2(al_e[e] - m2[d]) * inv_l[d]; al streamed, one random line
__global__ __launch_bounds__(256) void att_edge(const int* __restrict__ ei,
                                                const float* __restrict__ al_e,
                                                const float* __restrict__ pack,
                                                float* __restrict__ att_out, int E) {
    int e = blockIdx.x * 256 + threadIdx.x;
    if (e >= E) return;
    int d = ei[E + e];
    float4v al = *(const float4v*)(al_e + (size_t)e * 4);
    float4v mm = *(const float4v*)(pack + (size_t)d * 8);
    float4v gg = *(const float4v*)(pack + (size_t)d * 8 + 4);
    float4v o;
#pragma unroll
    for (int h = 0; h < 4; ++h)
        o[h] = fexp2(al[h] - mm[h]) * gg[h];
    *(float4v*)(att_out + (size_t)e * 4) = o;
}

// ---------------- launcher ----------------
extern "C" void kernel_launch(void* const* d_in, const int* in_sizes, int n_in,
                              void* d_out, int out_size, void* d_ws, size_t ws_size,
                              hipStream_t stream) {
    const float* x     = (const float*)d_in[0];  // fp32 [N,256]
    const int*   ei    = (const int*)d_in[1];    // int32 [2,E]
    const float* W     = (const float*)d_in[2];  // fp32 [256,256]
    const float* att_s = (const float*)d_in[3];  // fp32 [4,64]
    const float* att_d = (const float*)d_in[4];  // fp32 [4,64]

    const int N = in_sizes[0] / IN_CH;   // 50000
    const int E = in_sizes[1] / 2;       // 800000

    char* ws = (char*)d_ws;
    size_t off = 0;
    unsigned short* xh_bf = (unsigned short*)(ws + off); off += (size_t)N * HC * 2;
    unsigned short* wt    = (unsigned short*)(ws + off); off += (size_t)IN_CH * HC * 2;
    float* a_src = (float*)(ws + off); off += (size_t)N * H_HEADS * 4;
    float* a_dst = (float*)(ws + off); off += (size_t)N * H_HEADS * 4;
    float* pack  = (float*)(ws + off); off += (size_t)N * 8 * 4;
    int* rowptr  = (int*)(ws + off); off += (size_t)N * 4;
    int* cursor  = (int*)(ws + off); off += (size_t)N * 4;
    int* csr_src = (int*)(ws + off); off += (size_t)E * 4;
    float* csr_al = (float*)(ws + off); off += (size_t)E * 4 * 4;
    float* al_e   = (float*)(ws + off); off += (size_t)E * 4 * 4;
    int* part    = (int*)(ws + off); off += 1024 * 4;   // scan partials
    size_t zoff = off;  // zero-init region
    int* deg     = (int*)(ws + off); off += (size_t)N * 4;

    float* out     = (float*)d_out;            // [N, 256] fp32
    float* out_att = out + (size_t)N * HC;     // [E, 4]   fp32

    (void)hipMemsetAsync(ws + zoff, 0, off - zoff, stream);  // deg only

    const int NB = (N + 1023) / 1024;          // scan blocks (49 for N=50000)

    prep_w<<<256, 256, 0, stream>>>(W, wt);
    deg_count<<<(E + 255) / 256, 256, 0, stream>>>(ei, deg, E);
    gemm_xh<<<(N + 15) / 16, 256, 0, stream>>>(x, wt, att_s, att_d,
                                               xh_bf, a_src, a_dst, N);
    scan_part<<<NB, 256, 0, stream>>>(deg, part, N);
    scan_final<<<NB, 256, 0, stream>>>(deg, part, rowptr, cursor, N);
    fill_csr<<<(E + 255) / 256, 256, 0, stream>>>(ei, a_src, a_dst, cursor,
                                                  csr_src, csr_al, al_e, E);
    gat_gather<<<(N + 3) / 4, 256, 0, stream>>>(csr_src, csr_al, rowptr, deg,
                                                xh_bf, out, pack, N);
    att_edge<<<(E + 255) / 256, 256, 0, stream>>>(ei, al_e, pack, out_att, E);
}

// Round 6
// 322.647 us; speedup vs baseline: 1.3895x; 1.0047x over previous
//
#include <hip/hip_runtime.h>
#include <math.h>

// ---------------- constants (shapes fixed by the reference) ----------------
#define IN_CH   256
#define HC      256   // H*C
#define H_HEADS 4
#define NEG_SLOPE 0.2f
#define LOG2E   1.44269504088896f
#define DEFER_THR 12.0f   // base-2 defer-max threshold (2^12 = 4096, fp32-safe)
#define MINIT   -3.0e38f  // finite "-inf" so pad edges (al=-INF) are exact no-ops

typedef __attribute__((ext_vector_type(8))) short short8;
typedef __attribute__((ext_vector_type(4))) short short4v;
typedef __attribute__((ext_vector_type(4))) float float4v;

// ---------------- helpers ----------------
__device__ __forceinline__ float bf2f(unsigned short b) {
    return __uint_as_float(((unsigned)b) << 16);
}
__device__ __forceinline__ unsigned short f2bf(float f) {
    unsigned u = __float_as_uint(f);
    u += 0x7fffu + ((u >> 16) & 1u);    // round-to-nearest-even
    return (unsigned short)(u >> 16);
}
__device__ __forceinline__ float lrelu(float a) {
    return a >= 0.f ? a : NEG_SLOPE * a;
}
// base-2 exp: single v_exp_f32 (natively 2^x on gfx950).
__device__ __forceinline__ float fexp2(float a) {
    return __builtin_amdgcn_exp2f(a);
}

// ---------------- kernels ----------------

// W (fp32, [256k x 256c] row-major) -> transposed bf16 (wt[c][k])
__global__ void prep_w(const float* __restrict__ w,
                       unsigned short* __restrict__ wt) {
    int idx = blockIdx.x * 256 + threadIdx.x;   // 65536 total
    int k = idx >> 8, c = idx & 255;
    wt[(size_t)c * 256 + k] = f2bf(w[idx]);
}

// xh = x @ W. Block = 16 rows x 256 cols (4 waves = 4 heads).
// Stages fp32 x directly; bf16 hi/lo split done in-register during staging.
// Epilogue fuses node_attn; att vectors pre-scaled by LOG2E so all logits
// live in base-2 domain (consumers use exp2).
__global__ __launch_bounds__(256) void gemm_xh(const float* __restrict__ x,
                                               const unsigned short* __restrict__ wt,
                                               const float* __restrict__ att_s,
                                               const float* __restrict__ att_d,
                                               unsigned short* __restrict__ xh_bf,
                                               float* __restrict__ a_src,
                                               float* __restrict__ a_dst, int N) {
    __shared__ __attribute__((aligned(16))) unsigned char lds_a[16384];
    int tid  = threadIdx.x;
    int wave = tid >> 6;            // == head index
    int lane = tid & 63;
    int quad = lane >> 4;
    int l16  = lane & 15;
    int rb   = blockIdx.x * 16;

    // ---- stage A-tile: 512 chunks x 8 floats -> hi/lo short8 slots ----
#pragma unroll
    for (int pass = 0; pass < 2; ++pass) {
        int s  = pass * 256 + tid;              // 0..511
        int kc = s >> 4;                        // 16-B chunk index (k/8)
        int m  = s & 15;                        // row within tile
        int grow = rb + m; if (grow >= N) grow = N - 1;
        const float* gp = x + (size_t)grow * IN_CH + kc * 8;
        float4v f0 = *(const float4v*)gp;
        float4v f1 = *(const float4v*)(gp + 4);
        short8 hi, lo;
#pragma unroll
        for (int j = 0; j < 4; ++j) {
            unsigned short h0 = f2bf(f0[j]);
            hi[j] = (short)h0;
            lo[j] = (short)f2bf(f0[j] - bf2f(h0));
            unsigned short h1 = f2bf(f1[j]);
            hi[4 + j] = (short)h1;
            lo[4 + j] = (short)f2bf(f1[j] - bf2f(h1));
        }
        *(short8*)(lds_a + (size_t)s * 16) = hi;
        *(short8*)(lds_a + 8192 + (size_t)s * 16) = lo;
    }
    __syncthreads();

    // ---- K-loop: 8 x { 2 ds_read_b128 + 4 x (1 B-load + 2 MFMA) } ----
    float4v acc[4] = {};
    const unsigned short* wt_base = wt + ((size_t)wave * 64 + l16) * IN_CH;
#pragma unroll
    for (int k0 = 0; k0 < 8; ++k0) {
        int kc   = k0 * 4 + quad;
        int slot = kc * 16 + l16;
        short8 a_hi = *(const short8*)(lds_a + slot * 16);
        short8 a_lo = *(const short8*)(lds_a + 8192 + slot * 16);
#pragma unroll
        for (int ct = 0; ct < 4; ++ct) {
            short8 bh = *(const short8*)(wt_base + (size_t)ct * 16 * IN_CH
                                         + k0 * 32 + quad * 8);
            acc[ct] = __builtin_amdgcn_mfma_f32_16x16x32_bf16(a_lo, bh, acc[ct], 0, 0, 0);
            acc[ct] = __builtin_amdgcn_mfma_f32_16x16x32_bf16(a_hi, bh, acc[ct], 0, 0, 0);
        }
    }

    // ---- epilogue: xh store + fused a_src/a_dst (head = wave, base-2) ----
    int cb = wave;
    float ps[4] = {0.f, 0.f, 0.f, 0.f};
    float pd[4] = {0.f, 0.f, 0.f, 0.f};
#pragma unroll
    for (int ct = 0; ct < 4; ++ct) {
        float as_c = att_s[cb * 64 + ct * 16 + l16] * LOG2E;
        float ad_c = att_d[cb * 64 + ct * 16 + l16] * LOG2E;
#pragma unroll
        for (int r = 0; r < 4; ++r) {
            float v = acc[ct][r];
            int grow = rb + quad * 4 + r;
            if (grow < N)
                xh_bf[(size_t)grow * HC + cb * 64 + ct * 16 + l16] = f2bf(v);
            ps[r] += v * as_c;
            pd[r] += v * ad_c;
        }
    }
#pragma unroll
    for (int off = 1; off < 16; off <<= 1) {
#pragma unroll
        for (int r = 0; r < 4; ++r) {
            ps[r] += __shfl_xor(ps[r], off);
            pd[r] += __shfl_xor(pd[r], off);
        }
    }
    if (l16 == 0) {
#pragma unroll
        for (int r = 0; r < 4; ++r) {
            int grow = rb + quad * 4 + r;
            if (grow < N) {
                a_src[(size_t)grow * 4 + cb] = ps[r];
                a_dst[(size_t)grow * 4 + cb] = pd[r];
            }
        }
    }
}

// degree histogram over dst
__global__ __launch_bounds__(256) void deg_count(const int* __restrict__ ei,
                                                 int* __restrict__ deg, int E) {
    int e = blockIdx.x * 256 + threadIdx.x;
    if (e >= E) return;
    atomicAdd(deg + ei[E + e], 1);
}

// ---- device-wide exclusive scan of deg[N] -> rowptr, cursor (2 phases) ----

// phase 1: per-block sums (1024 elements / block)
__global__ __launch_bounds__(256) void scan_part(const int* __restrict__ deg,
                                                 int* __restrict__ part, int N) {
    int t = threadIdx.x;
    int base = blockIdx.x * 1024 + t * 4;
    int s = 0;
    if (base + 4 <= N) {
        int4 v = *(const int4*)(deg + base);
        s = v.x + v.y + v.z + v.w;
    } else {
#pragma unroll
        for (int j = 0; j < 4; ++j)
            if (base + j < N) s += deg[base + j];
    }
#pragma unroll
    for (int off = 1; off < 64; off <<= 1) s += __shfl_xor(s, off);
    __shared__ int ws[4];
    if ((t & 63) == 0) ws[t >> 6] = s;
    __syncthreads();
    if (t == 0) part[blockIdx.x] = ws[0] + ws[1] + ws[2] + ws[3];
}

// phase 2: block offset = sum(part[0..bid)) computed in-block (NB ~ 49),
// then local exclusive scan, write rowptr & cursor.
__global__ __launch_bounds__(256) void scan_final(const int* __restrict__ deg,
                                                  const int* __restrict__ part,
                                                  int* __restrict__ rowptr,
                                                  int* __restrict__ cursor, int N) {
    __shared__ int sm[256];
    __shared__ int wsum[4];
    int t = threadIdx.x;
    int bacc = 0;
    for (int j = t; j < blockIdx.x; j += 256) bacc += part[j];
#pragma unroll
    for (int off = 1; off < 64; off <<= 1) bacc += __shfl_xor(bacc, off);
    if ((t & 63) == 0) wsum[t >> 6] = bacc;

    int base = blockIdx.x * 1024 + t * 4;
    int v0 = 0, v1 = 0, v2 = 0, v3 = 0;
    if (base + 4 <= N) {
        int4 v = *(const int4*)(deg + base);
        v0 = v.x; v1 = v.y; v2 = v.z; v3 = v.w;
    } else {
        if (base + 0 < N) v0 = deg[base + 0];
        if (base + 1 < N) v1 = deg[base + 1];
        if (base + 2 < N) v2 = deg[base + 2];
        if (base + 3 < N) v3 = deg[base + 3];
    }
    int s = v0 + v1 + v2 + v3;
    sm[t] = s;
    __syncthreads();
    for (int off = 1; off < 256; off <<= 1) {
        int tmp = (t >= off) ? sm[t - off] : 0;
        __syncthreads();
        sm[t] += tmp;
        __syncthreads();
    }
    int boff = wsum[0] + wsum[1] + wsum[2] + wsum[3];
    int run = boff + sm[t] - s;   // exclusive prefix for this thread
    int r0 = run, r1 = r0 + v0, r2 = r1 + v1, r3 = r2 + v2;
    if (base + 4 <= N) {
        *(int4*)(rowptr + base) = (int4){r0, r1, r2, r3};
        *(int4*)(cursor + base) = (int4){r0, r1, r2, r3};
    } else {
        if (base + 0 < N) { rowptr[base + 0] = r0; cursor[base + 0] = r0; }
        if (base + 1 < N) { rowptr[base + 1] = r1; cursor[base + 1] = r1; }
        if (base + 2 < N) { rowptr[base + 2] = r2; cursor[base + 2] = r2; }
        if (base + 3 < N) { rowptr[base + 3] = r3; cursor[base + 3] = r3; }
    }
}

// fill CSR + precompute per-edge logits (base-2, lrelu applied).
// csr_off holds PRE-SHIFTED byte offsets (src * 512) so the gather's
// address math is a single add. csr_al slot-ordered; al_e edge-ordered.
__global__ __launch_bounds__(256) void fill_csr(const int* __restrict__ ei,
                                                const float* __restrict__ a_src,
                                                const float* __restrict__ a_dst,
                                                int* __restrict__ cursor,
                                                int* __restrict__ csr_off,
                                                float* __restrict__ csr_al,
                                                float* __restrict__ al_e, int E) {
    int e = blockIdx.x * 256 + threadIdx.x;
    if (e >= E) return;
    int s = ei[e], d = ei[E + e];
    float4v as = *(const float4v*)(a_src + (size_t)s * 4);
    float4v ad = *(const float4v*)(a_dst + (size_t)d * 4);
    float4v al;
#pragma unroll
    for (int h = 0; h < 4; ++h) al[h] = lrelu(as[h] + ad[h]);
    int slot = atomicAdd(cursor + d, 1);
    csr_off[slot] = s << 9;   // byte offset into xh_bf (HC*2 = 512 B/row)
    *(float4v*)(csr_al + (size_t)slot * 4) = al;
    *(float4v*)(al_e + (size_t)e * 4) = al;
}

// TWO dsts per wave: lanes 0-31 -> d0, lanes 32-63 -> d1; each lane owns
// 8 channels (short8, 16 B). Every wave instruction advances 2 edges
// (E/O unroll -> 4 edge-instances per iteration): halves VALU per edge vs
// the 1-dst/wave version. Loop to max(cnt0,cnt1) with fully-predicated
// padding: pad al = -INF, pad off = 0, m_init = MINIT (finite) so pads are
// exact no-ops (exp2(-INF - m) = 0) and cnt==0 dsts emit out=0 naturally.
__global__ __launch_bounds__(256) void gat_gather(const int* __restrict__ csr_off,
                                                  const float* __restrict__ csr_al,
                                                  const int* __restrict__ rowptr,
                                                  const int* __restrict__ deg,
                                                  const unsigned short* __restrict__ xh_bf,
                                                  float* __restrict__ out,
                                                  float* __restrict__ pack, int N) {
    int wave = threadIdx.x >> 6, lane = threadIdx.x & 63;
    int half = lane >> 5;           // 0 -> d0, 1 -> d1
    int l32  = lane & 31;
    int h    = l32 >> 3;            // head (8 lanes per head)
    int d    = blockIdx.x * 8 + wave * 2 + half;
    bool dv  = d < N;
    int dc   = dv ? d : N - 1;
    int start = rowptr[dc];
    int cnt   = dv ? deg[dc] : 0;
    int cntMax = max(cnt, __shfl_xor(cnt, 32));

    const char* xb = (const char*)xh_bf;
    int lboff = l32 * 16;

    float mE = MINIT, lE = 0.f, mO = MINIT, lO = 0.f;
    float accE[8] = {0.f, 0.f, 0.f, 0.f, 0.f, 0.f, 0.f, 0.f};
    float accO[8] = {0.f, 0.f, 0.f, 0.f, 0.f, 0.f, 0.f, 0.f};

#define LOFF(idx) (((idx) < cnt) ? csr_off[start + (idx)] : 0)
#define LAL(idx)  (((idx) < cnt) ? csr_al[(size_t)(start + (idx)) * 4 + h] : -INFINITY)

    int oE = LOFF(0), oO = LOFF(1);
    float alE = LAL(0), alO = LAL(1);
    short8 xvE = *(const short8*)(xb + (size_t)oE + lboff);
    short8 xvO = *(const short8*)(xb + (size_t)oO + lboff);
    int oE2 = LOFF(2), oO2 = LOFF(3);

    for (int i = 0; i < cntMax; i += 2) {
        // prefetch data for edges i+2/i+3; offsets for i+4/i+5
        float alE_n = LAL(i + 2), alO_n = LAL(i + 3);
        short8 xvE_n = *(const short8*)(xb + (size_t)oE2 + lboff);
        short8 xvO_n = *(const short8*)(xb + (size_t)oO2 + lboff);
        int oE3 = LOFF(i + 4), oO3 = LOFF(i + 5);

        bool ok = (alE <= mE + DEFER_THR) && (alO <= mO + DEFER_THR);
        if (__all(ok)) {
            // fast path: stale max, no rescale (pads: p = 0)
            float p = fexp2(alE - mE);
            float q = fexp2(alO - mO);
            lE += p; lO += q;
#pragma unroll
            for (int j = 0; j < 8; ++j) {
                accE[j] += p * bf2f((unsigned short)xvE[j]);
                accO[j] += q * bf2f((unsigned short)xvO[j]);
            }
        } else {
            // slow path: classic online-softmax rescale
            float mnE = fmaxf(mE, alE);
            float scE = fexp2(mE - mnE);
            float pE  = fexp2(alE - mnE);
            lE = lE * scE + pE;
            float mnO = fmaxf(mO, alO);
            float scO = fexp2(mO - mnO);
            float pO  = fexp2(alO - mnO);
            lO = lO * scO + pO;
#pragma unroll
            for (int j = 0; j < 8; ++j) {
                accE[j] = accE[j] * scE + pE * bf2f((unsigned short)xvE[j]);
                accO[j] = accO[j] * scO + pO * bf2f((unsigned short)xvO[j]);
            }
            mE = mnE; mO = mnO;
        }
        alE = alE_n; alO = alO_n; xvE = xvE_n; xvO = xvO_n;
        oE2 = oE3; oO2 = oO3;
    }
#undef LOFF
#undef LAL

    // merge E/O states (exact for stale maxes; cnt==0 -> l=0 -> o=0)
    float mm = fmaxf(mE, mO);
    float sE = fexp2(mE - mm), sO = fexp2(mO - mm);
    float l  = lE * sE + lO * sO;
    float inv = 1.f / (l + 1e-16f);
    if (dv) {
        float4v o0, o1;
#pragma unroll
        for (int j = 0; j < 4; ++j) {
            o0[j] = (accE[j] * sE + accO[j] * sO) * inv;
            o1[j] = (accE[4 + j] * sE + accO[4 + j] * sO) * inv;
        }
        float* orow = out + (size_t)d * HC + l32 * 8;
        *(float4v*)orow = o0;
        *(float4v*)(orow + 4) = o1;
        if ((l32 & 7) == 0) {
            pack[(size_t)d * 8 + h]     = mm;
            pack[(size_t)d * 8 + 4 + h] = inv;
        }
    }
}

// att[e,:] = exp2(al_e[e] - m2[d]) * inv_l[d]; al streamed, one random line
__global__ __launch_bounds__(256) void att_edge(const int* __restrict__ ei,
                                                const float* __restrict__ al_e,
                                                const float* __restrict__ pack,
                                                float* __restrict__ att_out, int E) {
    int e = blockIdx.x * 256 + threadIdx.x;
    if (e >= E) return;
    int d = ei[E + e];
    float4v al = *(const float4v*)(al_e + (size_t)e * 4);
    float4v mm = *(const float4v*)(pack + (size_t)d * 8);
    float4v gg = *(const float4v*)(pack + (size_t)d * 8 + 4);
    float4v o;
#pragma unroll
    for (int h = 0; h < 4; ++h)
        o[h] = fexp2(al[h] - mm[h]) * gg[h];
    *(float4v*)(att_out + (size_t)e * 4) = o;
}

// ---------------- launcher ----------------
extern "C" void kernel_launch(void* const* d_in, const int* in_sizes, int n_in,
                              void* d_out, int out_size, void* d_ws, size_t ws_size,
                              hipStream_t stream) {
    const float* x     = (const float*)d_in[0];  // fp32 [N,256]
    const int*   ei    = (const int*)d_in[1];    // int32 [2,E]
    const float* W     = (const float*)d_in[2];  // fp32 [256,256]
    const float* att_s = (const float*)d_in[3];  // fp32 [4,64]
    const float* att_d = (const float*)d_in[4];  // fp32 [4,64]

    const int N = in_sizes[0] / IN_CH;   // 50000
    const int E = in_sizes[1] / 2;       // 800000

    char* ws = (char*)d_ws;
    size_t off = 0;
    unsigned short* xh_bf = (unsigned short*)(ws + off); off += (size_t)N * HC * 2;
    unsigned short* wt    = (unsigned short*)(ws + off); off += (size_t)IN_CH * HC * 2;
    float* a_src = (float*)(ws + off); off += (size_t)N * H_HEADS * 4;
    float* a_dst = (float*)(ws + off); off += (size_t)N * H_HEADS * 4;
    float* pack  = (float*)(ws + off); off += (size_t)N * 8 * 4;
    int* rowptr  = (int*)(ws + off); off += (size_t)N * 4;
    int* cursor  = (int*)(ws + off); off += (size_t)N * 4;
    int* csr_off = (int*)(ws + off); off += (size_t)E * 4;
    float* csr_al = (float*)(ws + off); off += (size_t)E * 4 * 4;
    float* al_e   = (float*)(ws + off); off += (size_t)E * 4 * 4;
    int* part    = (int*)(ws + off); off += 1024 * 4;   // scan partials
    size_t zoff = off;  // zero-init region
    int* deg     = (int*)(ws + off); off += (size_t)N * 4;

    float* out     = (float*)d_out;            // [N, 256] fp32
    float* out_att = out + (size_t)N * HC;     // [E, 4]   fp32

    (void)hipMemsetAsync(ws + zoff, 0, off - zoff, stream);  // deg only

    const int NB = (N + 1023) / 1024;          // scan blocks (49 for N=50000)

    prep_w<<<256, 256, 0, stream>>>(W, wt);
    deg_count<<<(E + 255) / 256, 256, 0, stream>>>(ei, deg, E);
    gemm_xh<<<(N + 15) / 16, 256, 0, stream>>>(x, wt, att_s, att_d,
                                               xh_bf, a_src, a_dst, N);
    scan_part<<<NB, 256, 0, stream>>>(deg, part, N);
    scan_final<<<NB, 256, 0, stream>>>(deg, part, rowptr, cursor, N);
    fill_csr<<<(E + 255) / 256, 256, 0, stream>>>(ei, a_src, a_dst, cursor,
                                                  csr_off, csr_al, al_e, E);
    gat_gather<<<(N + 7) / 8, 256, 0, stream>>>(csr_off, csr_al, rowptr, deg,
                                                xh_bf, out, pack, N);
    att_edge<<<(E + 255) / 256, 256, 0, stream>>>(ei, al_e, pack, out_att, E);
}